// Round 16
// baseline (442.645 us; speedup 1.0000x reference)
//
#include <hip/hip_runtime.h>
#include <hip/hip_bf16.h>
#include <stdint.h>

#define B_SZ   512
#define NINST  4
#define D_IN   1024
#define D_OUTD 1024
#define CCOMP  64
#define MRANK  256
#define KTOT   (CCOMP*MRANK)   // 16384

typedef __attribute__((ext_vector_type(4))) float  f32x4;
typedef __attribute__((ext_vector_type(8))) __bf16 bf16x8;
typedef __attribute__((ext_vector_type(4))) __bf16 bf16x4;

__device__ inline void gload16(const void* g, void* l) {
  __builtin_amdgcn_global_load_lds(
      (const __attribute__((address_space(1))) void*)g,
      (__attribute__((address_space(3))) void*)l, 16, 0, 0);
}

// Counted-vmcnt barrier (T4): keep the newest N VMEM ops in flight.
#define BARN(N) do { \
  asm volatile("s_waitcnt lgkmcnt(0) vmcnt(" #N ")" ::: "memory"); \
  __builtin_amdgcn_sched_barrier(0); \
  __builtin_amdgcn_s_barrier(); \
  __builtin_amdgcn_sched_barrier(0); } while (0)

// ---------------------------------------------------------------------------
// Prepass: xbf[i][b][k] = bf16(x[b][i][k]).
// ---------------------------------------------------------------------------
__global__ __launch_bounds__(256)
void xcvt_kernel(const float* __restrict__ x, __bf16* __restrict__ xbf)
{
  const int total = (B_SZ*NINST*D_IN) / 4;
  for (int v = blockIdx.x*256 + threadIdx.x; v < total; v += gridDim.x*256) {
    const int k4 = v & 255;
    const int i  = (v >> 8) & 3;
    const int b  = v >> 10;
    f32x4 f = ((const f32x4*)x)[v];
    bf16x4 h; h[0]=(__bf16)f.x; h[1]=(__bf16)f.y; h[2]=(__bf16)f.z; h[3]=(__bf16)f.w;
    ((bf16x4*)xbf)[((size_t)i*B_SZ + b)*256 + k4] = h;
  }
}

// ---------------------------------------------------------------------------
// Phase 1, 256^2 T4 port (p2-R15 skeleton): inner = mask * (xbf . A).
// Tile 256(b) x 256(m = one full c), seg-batch 2 c's -> 32 steps, BK=64,
// 512 thr = 8 waves (2Mx4N), per-wave 128x64 out (acc 8x4).
// Xs: 3 slots via global_load_lds, DMA issued AFTER the A-loads each step so
// it is the NEWEST 4 vmem ops -> writeA's auto-wait is vmcnt(4) and the
// prefetch crosses the barrier (T4).  As: 2 bufs, fp32 reg-staged, XOR write.
// LDS 160 KiB, 1 block/CU, grid 256 XCD-chunked.
// ---------------------------------------------------------------------------
__global__ __launch_bounds__(512, 1)
void p1_kernel(const __bf16* __restrict__ xbf, const float* __restrict__ A,
               const int* __restrict__ mask, __bf16* __restrict__ inner)
{
  const int bid = blockIdx.x;
  const int L   = (bid & 7) * 32 + (bid >> 3);   // grid 256, XCD-chunked
  const int bt  = L & 1;
  const int icg = L >> 1;          // 0..127
  const int ic0 = icg * 2;         // 2 consecutive c, same i
  const int i   = ic0 >> 6;
  const int c0  = ic0 & 63;
  const int b0  = bt * 256;
  const int NSTEP = 32;            // 2 segs x 16 K-steps

  const int tid  = threadIdx.x;
  const int lane = tid & 63;
  const int wid  = tid >> 6;       // 0..7
  const int wr   = wid >> 2;       // 0..1 : 128-row strip
  const int wc   = wid & 3;        // 0..3 : 64-col strip

  // Xs [3][256][64] bf16 (96 KB) + As [2][256][64] bf16 (64 KB) = 160 KiB.
  __shared__ __align__(16) char smem[163840];
  __bf16* Xs = (__bf16*)smem;
  __bf16* As = (__bf16*)(smem + 98304);

  f32x4 acc[8][4];
#pragma unroll
  for (int a_ = 0; a_ < 8; ++a_)
#pragma unroll
    for (int b_ = 0; b_ < 4; ++b_)
      acc[a_][b_] = (f32x4){0.f, 0.f, 0.f, 0.f};

  const __bf16* xbase  = xbf + ((size_t)i * B_SZ + b0) * D_IN;
  const float*  Abase0 = A + (size_t)ic0 * D_IN * MRANK;

  const int bo = tid & 255;        // m column (256)
  const int bg = tid >> 8;         // 0..1 -> octets bg*4..bg*4+3
  float areg[4][8];

  auto stageX = [&](int slot, int kt) {      // 256 rows x 64 k bf16, DMA
#pragma unroll
    for (int q = 0; q < 4; ++q) {
      const int u   = wid*4 + q;             // 0..31, wave-uniform
      const int row = u*8 + (lane >> 3);
      const int kch = (lane & 7) ^ (row & 7);
      gload16(xbase + (size_t)row * D_IN + (kt & 15)*64 + kch*8,
              Xs + slot*16384 + u*512);
    }
  };
  auto loadA = [&](int kt) {
    const float* Ab = Abase0 + (size_t)(kt >> 4) * D_IN * MRANK;
#pragma unroll
    for (int q = 0; q < 4; ++q)
#pragma unroll
      for (int j = 0; j < 8; ++j)
        areg[q][j] = Ab[(size_t)((kt & 15)*64 + (bg*4+q)*8 + j)*MRANK + bo];
  };
  auto writeA = [&](int buf) {
#pragma unroll
    for (int q = 0; q < 4; ++q) {
      const int oct = bg*4 + q;
      bf16x8 h;
#pragma unroll
      for (int j = 0; j < 8; ++j) h[j] = (__bf16)areg[q][j];
      *(bf16x8*)(As + buf*16384 + bo*64 + ((oct ^ (bo & 7)))*8) = h;
    }
  };
  auto computeStep = [&](int slot, int buf) {
#pragma unroll
    for (int kk = 0; kk < 2; ++kk) {
      const int oct = kk*4 + (lane >> 4);
      bf16x8 bf[4];
#pragma unroll
      for (int ni = 0; ni < 4; ++ni) {
        const int col = wc*64 + ni*16 + (lane & 15);
        bf[ni] = *(const bf16x8*)(As + buf*16384 + col*64 + ((oct ^ (col & 7)))*8);
      }
#pragma unroll
      for (int mh = 0; mh < 2; ++mh) {
        bf16x8 af[4];
#pragma unroll
        for (int mi = 0; mi < 4; ++mi) {
          const int row = wr*128 + (mh*4 + mi)*16 + (lane & 15);
          af[mi] = *(const bf16x8*)(Xs + slot*16384 + row*64 + ((oct ^ (row & 7)))*8);
        }
        __builtin_amdgcn_s_setprio(1);
#pragma unroll
        for (int ni = 0; ni < 4; ++ni)
#pragma unroll
          for (int mi = 0; mi < 4; ++mi)
            acc[mh*4+mi][ni] = __builtin_amdgcn_mfma_f32_16x16x32_bf16(
                af[mi], bf[ni], acc[mh*4+mi][ni], 0, 0, 0);
        __builtin_amdgcn_s_setprio(0);
      }
    }
  };
  auto segEpilogue = [&](int t) {
    const int c = c0 + (t >> 4);
    __bf16* obase = inner + ((size_t)i * B_SZ + b0) * KTOT + (size_t)c * MRANK;
#pragma unroll
    for (int mi = 0; mi < 8; ++mi) {
      float mv[4];
#pragma unroll
      for (int j = 0; j < 4; ++j) {
        const int row = wr*128 + mi*16 + (lane >> 4)*4 + j;
        mv[j] = (float)mask[(size_t)(b0 + row) * (NINST*CCOMP) + i*CCOMP + c];
      }
#pragma unroll
      for (int ni = 0; ni < 4; ++ni) {
        const int colL = wc*64 + ni*16 + (lane & 15);
#pragma unroll
        for (int j = 0; j < 4; ++j) {
          const int rowL = wr*128 + mi*16 + (lane >> 4)*4 + j;
          obase[(size_t)rowL * KTOT + colL] = (__bf16)(acc[mi][ni][j] * mv[j]);
        }
#pragma unroll
        for (int j = 0; j < 4; ++j) acc[mi][ni][j] = 0.f;
      }
    }
  };

  // prologue: A(0) loads oldest, X(0), X(1) DMA newest; writeA waits vmcnt(8).
  loadA(0);
  stageX(0, 0);
  stageX(1, 1);
  writeA(0);
  BARN(4);                                   // drains X(0), keeps X(1)

  for (int t = 0; t < NSTEP; ++t) {
    const int slot = t % 3;
    const int buf  = t & 1;
    if (t+1 < NSTEP) loadA(t+1);             // oldest this step
    if (t+2 < NSTEP) stageX((t+2) % 3, t+2); // newest 4 -> crosses barrier
    computeStep(slot, buf);
    if (t+1 < NSTEP) writeA(buf ^ 1);        // auto vmcnt(4): keeps X(t+2)
    if ((t & 15) == 15) segEpilogue(t);      // stores; scrambles vmcnt
    if ((t & 15) == 15 || t >= NSTEP-2) BARN(0); else BARN(4);
  }
}

// ---------------------------------------------------------------------------
// Phase 2, 256^2 T4 (R15 + load-ordering fix): part[ks] = inner . Bflat slice.
// ---------------------------------------------------------------------------
__global__ __launch_bounds__(512, 1)
void p2_kernel(const __bf16* __restrict__ inner, const float* __restrict__ Bm,
               float* __restrict__ dst, int nks)
{
  const int bid = blockIdx.x;
  const int nwg = gridDim.x;
  const int L   = (bid & 7) * (nwg >> 3) + (bid >> 3);
  const int tile = L & 7;
  const int rest = L >> 3;          // i*nks + ks
  const int ks  = rest % nks;
  const int i   = rest / nks;
  const int mt  = tile & 1;
  const int nt  = tile >> 1;
  const int b0  = mt * 256;
  const int o0  = nt * 256;
  const int NSTEP = (KTOT/64) / nks;
  const int kb0   = ks * NSTEP;

  const int tid  = threadIdx.x;
  const int lane = tid & 63;
  const int wid  = tid >> 6;
  const int wr   = wid >> 2;
  const int wc   = wid & 3;

  __shared__ __align__(16) char smem[163840];
  __bf16* As = (__bf16*)smem;               // [3][256][64] DMA slots
  __bf16* Bs = (__bf16*)(smem + 98304);     // [2][256][64] reg-staged

  f32x4 acc[8][4];
#pragma unroll
  for (int a_ = 0; a_ < 8; ++a_)
#pragma unroll
    for (int b_ = 0; b_ < 4; ++b_)
      acc[a_][b_] = (f32x4){0.f, 0.f, 0.f, 0.f};

  const __bf16* ibase = inner + ((size_t)i * B_SZ + b0) * KTOT;
  const float*  Bbase = Bm + (size_t)i * KTOT * D_OUTD + o0;

  const int bo = tid & 255;
  const int bg = tid >> 8;
  float breg[4][8];

  auto stageA = [&](int slot, int kt) {
#pragma unroll
    for (int q = 0; q < 4; ++q) {
      const int u   = wid*4 + q;
      const int row = u*8 + (lane >> 3);
      const int kch = (lane & 7) ^ (row & 7);
      gload16(ibase + (size_t)row * KTOT + (size_t)(kb0 + kt)*64 + kch*8,
              As + slot*16384 + u*512);
    }
  };
  auto loadB = [&](int kt) {
#pragma unroll
    for (int q = 0; q < 4; ++q)
#pragma unroll
      for (int j = 0; j < 8; ++j)
        breg[q][j] = Bbase[(size_t)((size_t)(kb0 + kt)*64 + (bg*4+q)*8 + j)*D_OUTD + bo];
  };
  auto writeB = [&](int buf) {
#pragma unroll
    for (int q = 0; q < 4; ++q) {
      const int oct = bg*4 + q;
      bf16x8 h;
#pragma unroll
      for (int j = 0; j < 8; ++j) h[j] = (__bf16)breg[q][j];
      *(bf16x8*)(Bs + buf*16384 + bo*64 + ((oct ^ (bo & 7)))*8) = h;
    }
  };

  // prologue: B(0) loads oldest, A(0), A(1) DMA newest.
  loadB(0);
  stageA(0, 0);
  stageA(1, 1);
  writeB(0);                                 // auto vmcnt(8)
  BARN(4);                                   // drains A(0), keeps A(1)

  for (int t = 0; t < NSTEP; ++t) {
    const int aslot = t % 3;
    const int bbuf  = t & 1;
    if (t+1 < NSTEP) loadB(t+1);             // oldest this step
    if (t+2 < NSTEP) stageA((t+2) % 3, t+2); // newest 4 -> crosses barrier
#pragma unroll
    for (int kk = 0; kk < 2; ++kk) {
      const int oct = kk*4 + (lane >> 4);
      bf16x8 bf[4];
#pragma unroll
      for (int ni = 0; ni < 4; ++ni) {
        const int col = wc*64 + ni*16 + (lane & 15);
        bf[ni] = *(const bf16x8*)(Bs + bbuf*16384 + col*64 + ((oct ^ (col & 7)))*8);
      }
#pragma unroll
      for (int mh = 0; mh < 2; ++mh) {
        bf16x8 af[4];
#pragma unroll
        for (int mi = 0; mi < 4; ++mi) {
          const int row = wr*128 + (mh*4 + mi)*16 + (lane & 15);
          af[mi] = *(const bf16x8*)(As + aslot*16384 + row*64 + ((oct ^ (row & 7)))*8);
        }
        __builtin_amdgcn_s_setprio(1);
#pragma unroll
        for (int ni = 0; ni < 4; ++ni)
#pragma unroll
          for (int mi = 0; mi < 4; ++mi)
            acc[mh*4+mi][ni] = __builtin_amdgcn_mfma_f32_16x16x32_bf16(
                af[mi], bf[ni], acc[mh*4+mi][ni], 0, 0, 0);
        __builtin_amdgcn_s_setprio(0);
      }
    }
    if (t+1 < NSTEP) writeB(bbuf ^ 1);       // auto vmcnt(4): keeps A(t+2)
    if (t >= NSTEP-2) BARN(0); else BARN(4);
  }

  float* obase = dst + (size_t)ks * ((size_t)B_SZ*NINST*D_OUTD)
               + ((size_t)b0 * NINST + i) * D_OUTD + o0;
#pragma unroll
  for (int mi = 0; mi < 8; ++mi)
#pragma unroll
    for (int ni = 0; ni < 4; ++ni) {
      const int colL = wc*64 + ni*16 + (lane & 15);
#pragma unroll
      for (int j = 0; j < 4; ++j) {
        const int rowL = wr*128 + mi*16 + (lane >> 4)*4 + j;
        obase[(size_t)rowL * (NINST*D_OUTD) + colL] = acc[mi][ni][j];
      }
    }
}

__global__ __launch_bounds__(256)
void reduce_kernel(const float* __restrict__ part, float* __restrict__ out, int nks)
{
  const int total = (B_SZ*NINST*D_OUTD) / 4;
  for (int v = blockIdx.x*256 + threadIdx.x; v < total; v += gridDim.x*256) {
    f32x4 s = ((const f32x4*)part)[v];
    for (int ks = 1; ks < nks; ++ks)
      s += ((const f32x4*)part)[(size_t)ks*total + v];
    ((f32x4*)out)[v] = s;
  }
}

extern "C" void kernel_launch(void* const* d_in, const int* in_sizes, int n_in,
                              void* d_out, int out_size, void* d_ws, size_t ws_size,
                              hipStream_t stream) {
  const float* x    = (const float*)d_in[0];
  const float* A    = (const float*)d_in[1];
  const float* Bm   = (const float*)d_in[2];
  const int*   mask = (const int*)d_in[3];

  const size_t innerB = (size_t)NINST * B_SZ * KTOT * 2;       // 64 MB
  const size_t xbfB   = (size_t)NINST * B_SZ * D_IN * 2;       // 4 MB
  const size_t partB  = (size_t)B_SZ * NINST * D_OUTD * 4;     // 8 MB per split

  char* p = (char*)d_ws;
  __bf16* inner = (__bf16*)p;             p += innerB;
  __bf16* xbf   = (__bf16*)p;             p += xbfB;
  const size_t used = (size_t)(p - (char*)d_ws);

  int nks = 1;
  if      (ws_size >= used + 8*partB) nks = 8;
  else if (ws_size >= used + 4*partB) nks = 4;
  else if (ws_size >= used + 2*partB) nks = 2;
  float* part = (nks > 1) ? (float*)p : (float*)d_out;

  xcvt_kernel<<<dim3(1024),  dim3(256), 0, stream>>>(x, xbf);
  p1_kernel<<<dim3(256),     dim3(512), 0, stream>>>(xbf, A, mask, inner);
  p2_kernel<<<dim3(32*nks),  dim3(512), 0, stream>>>(inner, Bm, part, nks);
  if (nks > 1)
    reduce_kernel<<<dim3(1024), dim3(256), 0, stream>>>(part, (float*)d_out, nks);
}

// Round 17
// 223.281 us; speedup vs baseline: 1.9825x; 1.9825x over previous
//
#include <hip/hip_runtime.h>
#include <hip/hip_bf16.h>
#include <stdint.h>

#define B_SZ   512
#define NINST  4
#define D_IN   1024
#define D_OUTD 1024
#define CCOMP  64
#define MRANK  256
#define KTOT   (CCOMP*MRANK)   // 16384

typedef __attribute__((ext_vector_type(4))) float  f32x4;
typedef __attribute__((ext_vector_type(8))) __bf16 bf16x8;
typedef __attribute__((ext_vector_type(4))) __bf16 bf16x4;

__device__ inline void gload16(const void* g, void* l) {
  __builtin_amdgcn_global_load_lds(
      (const __attribute__((address_space(1))) void*)g,
      (__attribute__((address_space(3))) void*)l, 16, 0, 0);
}

// Counted-vmcnt barrier (T4): keep the newest N VMEM ops in flight.
#define BARN(N) do { \
  asm volatile("s_waitcnt lgkmcnt(0) vmcnt(" #N ")" ::: "memory"); \
  __builtin_amdgcn_sched_barrier(0); \
  __builtin_amdgcn_s_barrier(); \
  __builtin_amdgcn_sched_barrier(0); } while (0)

// ---------------------------------------------------------------------------
// Prepass: xbf[i][b][k] = bf16(x[b][i][k]).
// ---------------------------------------------------------------------------
__global__ __launch_bounds__(256)
void xcvt_kernel(const float* __restrict__ x, __bf16* __restrict__ xbf)
{
  const int total = (B_SZ*NINST*D_IN) / 4;
  for (int v = blockIdx.x*256 + threadIdx.x; v < total; v += gridDim.x*256) {
    const int k4 = v & 255;
    const int i  = (v >> 8) & 3;
    const int b  = v >> 10;
    f32x4 f = ((const f32x4*)x)[v];
    bf16x4 h; h[0]=(__bf16)f.x; h[1]=(__bf16)f.y; h[2]=(__bf16)f.z; h[3]=(__bf16)f.w;
    ((bf16x4*)xbf)[((size_t)i*B_SZ + b)*256 + k4] = h;
  }
}

// ---------------------------------------------------------------------------
// Phase 1, 256^2 T4, ONE c per block (epilogue OUTSIDE the loop so the loop
// body is token-identical to the proven p2): inner[i][b][c*256+m].
// Tile 256(b) x 256(m = full c), BK=64, NSTEP=16, 512 thr = 8 waves (2Mx4N),
// per-wave 128x64 (acc 8x4).  Xs: 3 DMA slots; As: 2 bufs fp32 reg-staged.
// LDS 160 KiB, 1 block/CU, grid 512 XCD-chunked (2 rounds).
// ---------------------------------------------------------------------------
__global__ __launch_bounds__(512, 1)
void p1_kernel(const __bf16* __restrict__ xbf, const float* __restrict__ A,
               const int* __restrict__ mask, __bf16* __restrict__ inner)
{
  const int bid = blockIdx.x;
  const int L   = (bid & 7) * 64 + (bid >> 3);   // grid 512, XCD-chunked
  const int bt  = L & 1;
  const int ic  = L >> 1;          // 0..255
  const int i   = ic >> 6;
  const int c   = ic & 63;
  const int b0  = bt * 256;
  const int NSTEP = 16;

  const int tid  = threadIdx.x;
  const int lane = tid & 63;
  const int wid  = tid >> 6;       // 0..7
  const int wr   = wid >> 2;       // 0..1 : 128-row strip
  const int wc   = wid & 3;        // 0..3 : 64-col strip

  // Xs [3][256][64] bf16 (96 KB) + As [2][256][64] bf16 (64 KB) = 160 KiB.
  __shared__ __align__(16) char smem[163840];
  __bf16* Xs = (__bf16*)smem;
  __bf16* As = (__bf16*)(smem + 98304);

  f32x4 acc[8][4];
#pragma unroll
  for (int a_ = 0; a_ < 8; ++a_)
#pragma unroll
    for (int b_ = 0; b_ < 4; ++b_)
      acc[a_][b_] = (f32x4){0.f, 0.f, 0.f, 0.f};

  const __bf16* xbase = xbf + ((size_t)i * B_SZ + b0) * D_IN;
  const float*  Abase = A + (size_t)ic * D_IN * MRANK;

  const int bo = tid & 255;        // m column (256)
  const int bg = tid >> 8;         // 0..1 -> octets bg*4..bg*4+3
  float areg[4][8];

  auto stageX = [&](int slot, int kt) {      // 256 rows x 64 k bf16, DMA
#pragma unroll
    for (int q = 0; q < 4; ++q) {
      const int u   = wid*4 + q;             // 0..31, wave-uniform
      const int row = u*8 + (lane >> 3);
      const int kch = (lane & 7) ^ (row & 7);
      gload16(xbase + (size_t)row * D_IN + kt*64 + kch*8,
              Xs + slot*16384 + u*512);
    }
  };
  auto loadA = [&](int kt) {
#pragma unroll
    for (int q = 0; q < 4; ++q)
#pragma unroll
      for (int j = 0; j < 8; ++j)
        areg[q][j] = Abase[(size_t)(kt*64 + (bg*4+q)*8 + j)*MRANK + bo];
  };
  auto writeA = [&](int buf) {
#pragma unroll
    for (int q = 0; q < 4; ++q) {
      const int oct = bg*4 + q;
      bf16x8 h;
#pragma unroll
      for (int j = 0; j < 8; ++j) h[j] = (__bf16)areg[q][j];
      *(bf16x8*)(As + buf*16384 + bo*64 + ((oct ^ (bo & 7)))*8) = h;
    }
  };

  // prologue: A(0) loads oldest, X(0), X(1) DMA newest; writeA waits vmcnt(8).
  loadA(0);
  stageX(0, 0);
  stageX(1, 1);
  writeA(0);
  BARN(4);                                   // drains X(0), keeps X(1)

#pragma unroll 1
  for (int t = 0; t < NSTEP; ++t) {
    const int slot = t % 3;
    const int buf  = t & 1;
    if (t+1 < NSTEP) loadA(t+1);             // oldest this step
    if (t+2 < NSTEP) stageX((t+2) % 3, t+2); // newest 4 -> crosses barrier
#pragma unroll
    for (int kk = 0; kk < 2; ++kk) {
      const int oct = kk*4 + (lane >> 4);
      bf16x8 bf[4];
#pragma unroll
      for (int ni = 0; ni < 4; ++ni) {
        const int col = wc*64 + ni*16 + (lane & 15);
        bf[ni] = *(const bf16x8*)(As + buf*16384 + col*64 + ((oct ^ (col & 7)))*8);
      }
#pragma unroll
      for (int mh = 0; mh < 2; ++mh) {
        bf16x8 af[4];
#pragma unroll
        for (int mi = 0; mi < 4; ++mi) {
          const int row = wr*128 + (mh*4 + mi)*16 + (lane & 15);
          af[mi] = *(const bf16x8*)(Xs + slot*16384 + row*64 + ((oct ^ (row & 7)))*8);
        }
        __builtin_amdgcn_s_setprio(1);
#pragma unroll
        for (int ni = 0; ni < 4; ++ni)
#pragma unroll
          for (int mi = 0; mi < 4; ++mi)
            acc[mh*4+mi][ni] = __builtin_amdgcn_mfma_f32_16x16x32_bf16(
                af[mi], bf[ni], acc[mh*4+mi][ni], 0, 0, 0);
        __builtin_amdgcn_s_setprio(0);
      }
    }
    if (t+1 < NSTEP) writeA(buf ^ 1);        // auto vmcnt(4): keeps X(t+2)
    if (t >= NSTEP-2) BARN(0); else BARN(4);
  }

  // ---- epilogue (outside loop): mask + bf16 stores ----
  __bf16* obase = inner + ((size_t)i * B_SZ + b0) * KTOT + (size_t)c * MRANK;
#pragma unroll
  for (int mi = 0; mi < 8; ++mi) {
    float mv[4];
#pragma unroll
    for (int j = 0; j < 4; ++j) {
      const int row = wr*128 + mi*16 + (lane >> 4)*4 + j;
      mv[j] = (float)mask[(size_t)(b0 + row) * (NINST*CCOMP) + i*CCOMP + c];
    }
#pragma unroll
    for (int ni = 0; ni < 4; ++ni) {
      const int colL = wc*64 + ni*16 + (lane & 15);
#pragma unroll
      for (int j = 0; j < 4; ++j) {
        const int rowL = wr*128 + mi*16 + (lane >> 4)*4 + j;
        obase[(size_t)rowL * KTOT + colL] = (__bf16)(acc[mi][ni][j] * mv[j]);
      }
    }
  }
}

// ---------------------------------------------------------------------------
// Phase 2, 256^2 T4 (R16 exact, ~75 us): part[ks] = inner . Bflat slice.
// ---------------------------------------------------------------------------
__global__ __launch_bounds__(512, 1)
void p2_kernel(const __bf16* __restrict__ inner, const float* __restrict__ Bm,
               float* __restrict__ dst, int nks)
{
  const int bid = blockIdx.x;
  const int nwg = gridDim.x;
  const int L   = (bid & 7) * (nwg >> 3) + (bid >> 3);
  const int tile = L & 7;
  const int rest = L >> 3;          // i*nks + ks
  const int ks  = rest % nks;
  const int i   = rest / nks;
  const int mt  = tile & 1;
  const int nt  = tile >> 1;
  const int b0  = mt * 256;
  const int o0  = nt * 256;
  const int NSTEP = (KTOT/64) / nks;
  const int kb0   = ks * NSTEP;

  const int tid  = threadIdx.x;
  const int lane = tid & 63;
  const int wid  = tid >> 6;
  const int wr   = wid >> 2;
  const int wc   = wid & 3;

  __shared__ __align__(16) char smem[163840];
  __bf16* As = (__bf16*)smem;               // [3][256][64] DMA slots
  __bf16* Bs = (__bf16*)(smem + 98304);     // [2][256][64] reg-staged

  f32x4 acc[8][4];
#pragma unroll
  for (int a_ = 0; a_ < 8; ++a_)
#pragma unroll
    for (int b_ = 0; b_ < 4; ++b_)
      acc[a_][b_] = (f32x4){0.f, 0.f, 0.f, 0.f};

  const __bf16* ibase = inner + ((size_t)i * B_SZ + b0) * KTOT;
  const float*  Bbase = Bm + (size_t)i * KTOT * D_OUTD + o0;

  const int bo = tid & 255;
  const int bg = tid >> 8;
  float breg[4][8];

  auto stageA = [&](int slot, int kt) {
#pragma unroll
    for (int q = 0; q < 4; ++q) {
      const int u   = wid*4 + q;
      const int row = u*8 + (lane >> 3);
      const int kch = (lane & 7) ^ (row & 7);
      gload16(ibase + (size_t)row * KTOT + (size_t)(kb0 + kt)*64 + kch*8,
              As + slot*16384 + u*512);
    }
  };
  auto loadB = [&](int kt) {
#pragma unroll
    for (int q = 0; q < 4; ++q)
#pragma unroll
      for (int j = 0; j < 8; ++j)
        breg[q][j] = Bbase[(size_t)((size_t)(kb0 + kt)*64 + (bg*4+q)*8 + j)*D_OUTD + bo];
  };
  auto writeB = [&](int buf) {
#pragma unroll
    for (int q = 0; q < 4; ++q) {
      const int oct = bg*4 + q;
      bf16x8 h;
#pragma unroll
      for (int j = 0; j < 8; ++j) h[j] = (__bf16)breg[q][j];
      *(bf16x8*)(Bs + buf*16384 + bo*64 + ((oct ^ (bo & 7)))*8) = h;
    }
  };

  // prologue: B(0) loads oldest, A(0), A(1) DMA newest.
  loadB(0);
  stageA(0, 0);
  stageA(1, 1);
  writeB(0);                                 // auto vmcnt(8)
  BARN(4);                                   // drains A(0), keeps A(1)

#pragma unroll 1
  for (int t = 0; t < NSTEP; ++t) {
    const int aslot = t % 3;
    const int bbuf  = t & 1;
    if (t+1 < NSTEP) loadB(t+1);             // oldest this step
    if (t+2 < NSTEP) stageA((t+2) % 3, t+2); // newest 4 -> crosses barrier
#pragma unroll
    for (int kk = 0; kk < 2; ++kk) {
      const int oct = kk*4 + (lane >> 4);
      bf16x8 bf[4];
#pragma unroll
      for (int ni = 0; ni < 4; ++ni) {
        const int col = wc*64 + ni*16 + (lane & 15);
        bf[ni] = *(const bf16x8*)(Bs + bbuf*16384 + col*64 + ((oct ^ (col & 7)))*8);
      }
#pragma unroll
      for (int mh = 0; mh < 2; ++mh) {
        bf16x8 af[4];
#pragma unroll
        for (int mi = 0; mi < 4; ++mi) {
          const int row = wr*128 + (mh*4 + mi)*16 + (lane & 15);
          af[mi] = *(const bf16x8*)(As + aslot*16384 + row*64 + ((oct ^ (row & 7)))*8);
        }
        __builtin_amdgcn_s_setprio(1);
#pragma unroll
        for (int ni = 0; ni < 4; ++ni)
#pragma unroll
          for (int mi = 0; mi < 4; ++mi)
            acc[mh*4+mi][ni] = __builtin_amdgcn_mfma_f32_16x16x32_bf16(
                af[mi], bf[ni], acc[mh*4+mi][ni], 0, 0, 0);
        __builtin_amdgcn_s_setprio(0);
      }
    }
    if (t+1 < NSTEP) writeB(bbuf ^ 1);       // auto vmcnt(4): keeps A(t+2)
    if (t >= NSTEP-2) BARN(0); else BARN(4);
  }

  float* obase = dst + (size_t)ks * ((size_t)B_SZ*NINST*D_OUTD)
               + ((size_t)b0 * NINST + i) * D_OUTD + o0;
#pragma unroll
  for (int mi = 0; mi < 8; ++mi)
#pragma unroll
    for (int ni = 0; ni < 4; ++ni) {
      const int colL = wc*64 + ni*16 + (lane & 15);
#pragma unroll
      for (int j = 0; j < 4; ++j) {
        const int rowL = wr*128 + mi*16 + (lane >> 4)*4 + j;
        obase[(size_t)rowL * (NINST*D_OUTD) + colL] = acc[mi][ni][j];
      }
    }
}

__global__ __launch_bounds__(256)
void reduce_kernel(const float* __restrict__ part, float* __restrict__ out, int nks)
{
  const int total = (B_SZ*NINST*D_OUTD) / 4;
  for (int v = blockIdx.x*256 + threadIdx.x; v < total; v += gridDim.x*256) {
    f32x4 s = ((const f32x4*)part)[v];
    for (int ks = 1; ks < nks; ++ks)
      s += ((const f32x4*)part)[(size_t)ks*total + v];
    ((f32x4*)out)[v] = s;
  }
}

extern "C" void kernel_launch(void* const* d_in, const int* in_sizes, int n_in,
                              void* d_out, int out_size, void* d_ws, size_t ws_size,
                              hipStream_t stream) {
  const float* x    = (const float*)d_in[0];
  const float* A    = (const float*)d_in[1];
  const float* Bm   = (const float*)d_in[2];
  const int*   mask = (const int*)d_in[3];

  const size_t innerB = (size_t)NINST * B_SZ * KTOT * 2;       // 64 MB
  const size_t xbfB   = (size_t)NINST * B_SZ * D_IN * 2;       // 4 MB
  const size_t partB  = (size_t)B_SZ * NINST * D_OUTD * 4;     // 8 MB per split

  char* p = (char*)d_ws;
  __bf16* inner = (__bf16*)p;             p += innerB;
  __bf16* xbf   = (__bf16*)p;             p += xbfB;
  const size_t used = (size_t)(p - (char*)d_ws);

  int nks = 1;
  if      (ws_size >= used + 8*partB) nks = 8;
  else if (ws_size >= used + 4*partB) nks = 4;
  else if (ws_size >= used + 2*partB) nks = 2;
  float* part = (nks > 1) ? (float*)p : (float*)d_out;

  xcvt_kernel<<<dim3(1024),  dim3(256), 0, stream>>>(x, xbf);
  p1_kernel<<<dim3(512),     dim3(512), 0, stream>>>(xbf, A, mask, inner);
  p2_kernel<<<dim3(32*nks),  dim3(512), 0, stream>>>(inner, Bm, part, nks);
  if (nks > 1)
    reduce_kernel<<<dim3(1024), dim3(256), 0, stream>>>(part, (float*)d_out, nks);
}